// Round 5
// baseline (276.245 us; speedup 1.0000x reference)
//
#include <hip/hip_runtime.h>

#define NBINS 256
#define BLOCK 256
#define BIN_SCALE (256.0f / 255.0f)   // torch.histc: width=(255-0)/256, idx=floor(x/width)

// d_out poisoned before timed replays -> zero all 512 floats ourselves.
__global__ void zero_out(float* __restrict__ out) {
    const int i = blockIdx.x * blockDim.x + threadIdx.x;
    if (i < 2 * NBINS) out[i] = 0.0f;
}

__global__ __launch_bounds__(BLOCK) void hist_kernel(const float* __restrict__ x,
                                                     float* __restrict__ out,
                                                     int n) {
    // Thread-private byte-counter histograms: no atomics, no RMW races.
    // Thread t owns priv[t*256 .. t*256+255]. 64 KB.
    __shared__ unsigned char priv[BLOCK * NBINS];
    __shared__ uint4 part[4][64];                 // per-wave partial sums, 4 KB

    unsigned char* __restrict__ mine = &priv[threadIdx.x * NBINS];

    // zero my private column (16 x uint4 stores); private -> no barrier needed
    uint4* mz = (uint4*)mine;
#pragma unroll
    for (int i = 0; i < NBINS / 16; ++i) mz[i] = make_uint4(0u, 0u, 0u, 0u);

    const int n4 = n >> 2;
    const float4* __restrict__ x4 = (const float4*)x;
    const int tid = blockIdx.x * BLOCK + threadIdx.x;
    const int stride = gridDim.x * BLOCK;

    for (int i = tid; i < n4; i += stride) {
        float4 v = x4[i];
        if (v.x >= 0.0f && v.x <= 255.0f) mine[min((int)(v.x * BIN_SCALE), NBINS - 1)]++;
        if (v.y >= 0.0f && v.y <= 255.0f) mine[min((int)(v.y * BIN_SCALE), NBINS - 1)]++;
        if (v.z >= 0.0f && v.z <= 255.0f) mine[min((int)(v.z * BIN_SCALE), NBINS - 1)]++;
        if (v.w >= 0.0f && v.w <= 255.0f) mine[min((int)(v.w * BIN_SCALE), NBINS - 1)]++;
    }
    // scalar tail
    for (int i = (n4 << 2) + tid; i < n; i += stride) {
        float v = x[i];
        if (v >= 0.0f && v <= 255.0f) mine[min((int)(v * BIN_SCALE), NBINS - 1)]++;
    }

    __syncthreads();

    // Stage 1: wave w sums bin-quad q=lane over threads t in [w*64, w*64+64).
    // dword index = t*64 + lane -> bank = lane%32 -> 2-way (free).
    const int lane = threadIdx.x & 63;
    const int w = threadIdx.x >> 6;
    const unsigned* pw = (const unsigned*)priv;
    unsigned s0 = 0, s1 = 0, s2 = 0, s3 = 0;
#pragma unroll 8
    for (int t = w * 64; t < w * 64 + 64; ++t) {
        unsigned u = pw[t * 64 + lane];
        s0 += u & 0xFFu;
        s1 += (u >> 8) & 0xFFu;
        s2 += (u >> 16) & 0xFFu;
        s3 += u >> 24;
    }
    part[w][lane] = make_uint4(s0, s1, s2, s3);
    __syncthreads();

    // Stage 2: wave 0 combines the 4 wave-partials; one global float atomic
    // per bin per block (exact: integer-valued, totals < 2^24).
    if (w == 0) {
        uint4 a = part[0][lane], b = part[1][lane], c = part[2][lane], d = part[3][lane];
        atomicAdd(&out[lane * 4 + 0], (float)(a.x + b.x + c.x + d.x));
        atomicAdd(&out[lane * 4 + 1], (float)(a.y + b.y + c.y + d.y));
        atomicAdd(&out[lane * 4 + 2], (float)(a.z + b.z + c.z + d.z));
        atomicAdd(&out[lane * 4 + 3], (float)(a.w + b.w + c.w + d.w));
    }
}

__global__ void count_kernel(const void* __restrict__ bs_raw,
                             float* __restrict__ out) {
    const int as_int = *(const int*)bs_raw;
    float bs;
    if (as_int >= 1 && as_int < (1 << 20)) {
        bs = (float)as_int;
    } else {
        bs = *(const float*)bs_raw;
    }
    out[NBINS + threadIdx.x] = bs * out[0];
}

extern "C" void kernel_launch(void* const* d_in, const int* in_sizes, int n_in,
                              void* d_out, int out_size, void* d_ws, size_t ws_size,
                              hipStream_t stream) {
    const void* bs_ptr;
    const float* x;
    int n;
    if (n_in >= 2 && in_sizes[0] == 1) {
        bs_ptr = d_in[0];
        x = (const float*)d_in[1];
        n = in_sizes[1];
    } else {
        bs_ptr = d_in[1];
        x = (const float*)d_in[0];
        n = in_sizes[0];
    }

    float* out = (float*)d_out;  // [256 hist | 256 count], float32

    // Grid sized so elements/thread <= ~200 (byte counters must stay < 256).
    int grid = 1024;
    long threads = (long)grid * BLOCK;
    long per = ((long)n + threads - 1) / threads;
    if (per > 200) grid = (int)(((long)n + (long)BLOCK * 200 - 1) / ((long)BLOCK * 200));

    zero_out<<<2, 256, 0, stream>>>(out);
    hist_kernel<<<grid, BLOCK, 0, stream>>>(x, out, n);
    count_kernel<<<1, NBINS, 0, stream>>>(bs_ptr, out);
}

// Round 6
// 220.031 us; speedup vs baseline: 1.2555x; 1.2555x over previous
//
#include <hip/hip_runtime.h>

#define NBINS 256
#define BLOCK 256
#define GRID 2048
#define NCOPY 32
#define BIN_SCALE (256.0f / 255.0f)   // torch.histc: width=(255-0)/256, idx=floor(x/width)

// d_out poisoned before timed replays -> zero all 512 floats ourselves.
__global__ void zero_out(float* __restrict__ out) {
    const int i = blockIdx.x * blockDim.x + threadIdx.x;
    if (i < 2 * NBINS) out[i] = 0.0f;
}

__global__ __launch_bounds__(BLOCK) void hist_kernel(const float* __restrict__ x,
                                                     float* __restrict__ out,
                                                     int n) {
    // 32 histogram copies, bank-private: slot(bin,c) at dword bin*32+c -> bank c.
    // Lane uses copy c = lane&31, so every ds_add_u32 hits bank==c: exactly
    // 2 lanes/bank per instruction (free), no cross-lane serialization.
    __shared__ unsigned int sh[NBINS * NCOPY];   // 32 KB

    const int c = threadIdx.x & 31;

    // zero: thread t clears dwords [t*32, t*32+32)
    {
        uint4* z = (uint4*)&sh[threadIdx.x * 32];
#pragma unroll
        for (int i = 0; i < 8; ++i) z[i] = make_uint4(0u, 0u, 0u, 0u);
    }
    __syncthreads();

    const int n4 = n >> 2;
    const float4* __restrict__ x4 = (const float4*)x;
    const int tid = blockIdx.x * BLOCK + threadIdx.x;
    const int stride = gridDim.x * BLOCK;

    for (int i = tid; i < n4; i += stride) {
        float4 v = x4[i];
        if (v.x >= 0.0f && v.x <= 255.0f)
            atomicAdd(&sh[min((int)(v.x * BIN_SCALE), NBINS - 1) * NCOPY + c], 1u);
        if (v.y >= 0.0f && v.y <= 255.0f)
            atomicAdd(&sh[min((int)(v.y * BIN_SCALE), NBINS - 1) * NCOPY + c], 1u);
        if (v.z >= 0.0f && v.z <= 255.0f)
            atomicAdd(&sh[min((int)(v.z * BIN_SCALE), NBINS - 1) * NCOPY + c], 1u);
        if (v.w >= 0.0f && v.w <= 255.0f)
            atomicAdd(&sh[min((int)(v.w * BIN_SCALE), NBINS - 1) * NCOPY + c], 1u);
    }
    // scalar tail
    for (int i = (n4 << 2) + tid; i < n; i += stride) {
        float v = x[i];
        if (v >= 0.0f && v <= 255.0f)
            atomicAdd(&sh[min((int)(v * BIN_SCALE), NBINS - 1) * NCOPY + c], 1u);
    }

    __syncthreads();

    // Epilogue: thread b sums its bin's 32 copies with rotated (conflict-free)
    // reads: slot index b*32 + (i+b)%32 -> bank (i+b)%32, distinct across lanes.
    const int b = threadIdx.x;
    unsigned int s = 0;
#pragma unroll
    for (int i = 0; i < NCOPY; ++i)
        s += sh[b * NCOPY + ((i + b) & 31)];

    // One global float atomic per bin per block. Exact: integers < 2^24.
    if (s) atomicAdd(&out[b], (float)s);
}

__global__ void count_kernel(const void* __restrict__ bs_raw,
                             float* __restrict__ out) {
    const int as_int = *(const int*)bs_raw;
    float bs;
    if (as_int >= 1 && as_int < (1 << 20)) {
        bs = (float)as_int;
    } else {
        bs = *(const float*)bs_raw;
    }
    out[NBINS + threadIdx.x] = bs * out[0];
}

extern "C" void kernel_launch(void* const* d_in, const int* in_sizes, int n_in,
                              void* d_out, int out_size, void* d_ws, size_t ws_size,
                              hipStream_t stream) {
    const void* bs_ptr;
    const float* x;
    int n;
    if (n_in >= 2 && in_sizes[0] == 1) {
        bs_ptr = d_in[0];
        x = (const float*)d_in[1];
        n = in_sizes[1];
    } else {
        bs_ptr = d_in[1];
        x = (const float*)d_in[0];
        n = in_sizes[0];
    }

    float* out = (float*)d_out;  // [256 hist | 256 count], float32

    zero_out<<<2, 256, 0, stream>>>(out);
    hist_kernel<<<GRID, BLOCK, 0, stream>>>(x, out, n);
    count_kernel<<<1, NBINS, 0, stream>>>(bs_ptr, out);
}

// Round 7
// 216.625 us; speedup vs baseline: 1.2752x; 1.0157x over previous
//
#include <hip/hip_runtime.h>

#define NBINS 256
#define BLOCK 64                 // one wave per block
#define NQUAD 64                 // 256 bins / 4 bins-per-dword
#define CNT_DW (NQUAD * 64)      // 4096 counter dwords
#define LDS_DW (CNT_DW + 64)     // + 64 dummy dwords (out-of-range sink)
#define BIN_SCALE (256.0f / 255.0f)  // torch.histc width=(255-0)/256; idx=floor(x/width)
#define CAP_F4 62                // max float4 per thread -> <=248 elems (byte counters <256)

__global__ void zero_out(float* __restrict__ out) {
    const int i = blockIdx.x * blockDim.x + threadIdx.x;
    if (i < 2 * NBINS) out[i] = 0.0f;
}

// element -> (counter dword index, packed byte increment); OOR -> lane-private dummy
__device__ __forceinline__ void classify(float v, int t, int& dw, unsigned& inc) {
    int idx = (int)(v * BIN_SCALE);      // trunc == floor for v>=0
    idx = idx < 255 ? idx : 255;         // x==255 -> last bin
    const bool ok = (v >= 0.0f) && (v <= 255.0f);
    const int d = ((((unsigned)idx) >> 2) << 6) + t;  // (bin/4)*64 + lane -> bank=lane&31
    dw = ok ? d : (CNT_DW + t);
    inc = 1u << ((idx & 3) << 3);
}

__global__ __launch_bounds__(BLOCK) void hist_kernel(const float* __restrict__ x,
                                                     unsigned int* __restrict__ partial,
                                                     float* __restrict__ out,
                                                     int n, int G, int use_ws) {
    __shared__ unsigned int cnt[LDS_DW];   // 16.6 KB: per-lane byte counters, bank-aligned
    const int t = threadIdx.x;             // == lane (1 wave/block)

    for (int i = t; i < LDS_DW; i += BLOCK) cnt[i] = 0u;
    __syncthreads();

    const int n4 = n >> 2;
    const float4* __restrict__ x4 = (const float4*)x;
    const int stride = G * BLOCK;
    int i = blockIdx.x * BLOCK + t;

    if (i < n4) {
        float4 v = x4[i];
        for (;;) {
            const int ni = i + stride;
            const bool more = ni < n4;
            float4 nv;
            if (more) nv = x4[ni];         // prefetch next: overlaps DS chain below

            int d0, d1, d2, d3; unsigned s0, s1, s2, s3;
            classify(v.x, t, d0, s0);
            classify(v.y, t, d1, s1);
            classify(v.z, t, d2, s2);
            classify(v.w, t, d3, s3);

            // 4 independent reads (one lgkm wait), then merged in-order writes.
            // Lane-private dwords -> no cross-lane races; in-order DS per wave
            // makes "last write carries the full sum" correct for duplicates.
            unsigned o0 = cnt[d0], o1 = cnt[d1], o2 = cnt[d2], o3 = cnt[d3];
            cnt[d0] = o0 + s0;
            cnt[d1] = o1 + s1 + (d1 == d0 ? s0 : 0u);
            cnt[d2] = o2 + s2 + (d2 == d0 ? s0 : 0u) + (d2 == d1 ? s1 : 0u);
            cnt[d3] = o3 + s3 + (d3 == d0 ? s0 : 0u) + (d3 == d1 ? s1 : 0u)
                              + (d3 == d2 ? s2 : 0u);

            if (!more) break;
            v = nv; i = ni;
        }
    }
    // scalar tail (n not divisible by 4): single RMW each
    for (int j = (n4 << 2) + blockIdx.x * BLOCK + t; j < n; j += stride) {
        int dw; unsigned inc;
        classify(x[j], t, dw, inc);
        cnt[dw] += inc;
    }
    __syncthreads();

    // Epilogue: lane L sums bin-quad L over all 64 lanes' slices.
    // Rotated reads: addr L*64+((L+k)&63) -> 2 lanes/bank (free).
    unsigned accA = 0, accB = 0;   // packed u16 pairs: bytes{0,2} / bytes{1,3}
#pragma unroll 16
    for (int k = 0; k < 64; ++k) {
        unsigned u = cnt[(t << 6) + ((t + k) & 63)];
        accA += u & 0x00FF00FFu;
        accB += (u >> 8) & 0x00FF00FFu;
    }
    const unsigned b0 = accA & 0xFFFFu, b2 = accA >> 16;
    const unsigned b1 = accB & 0xFFFFu, b3 = accB >> 16;

    if (use_ws) {
        // coalesced 1 KB store: partial[block][bin]
        ((uint4*)(partial + (size_t)blockIdx.x * NBINS))[t] = make_uint4(b0, b1, b2, b3);
    } else {
        if (b0) atomicAdd(&out[4 * t + 0], (float)b0);
        if (b1) atomicAdd(&out[4 * t + 1], (float)b1);
        if (b2) atomicAdd(&out[4 * t + 2], (float)b2);
        if (b3) atomicAdd(&out[4 * t + 3], (float)b3);
    }
}

// 256 blocks; block j sums a g-slice (coalesced 1KB reads), <=256 atomics/bin total.
__global__ __launch_bounds__(NBINS) void reduce_kernel(const unsigned int* __restrict__ partial,
                                                       float* __restrict__ out,
                                                       int G, int slice) {
    const int bin = threadIdx.x;
    const int g0 = blockIdx.x * slice;
    const int g1 = (g0 + slice < G) ? (g0 + slice) : G;
    unsigned s = 0;
    for (int g = g0; g < g1; ++g)
        s += partial[(size_t)g * NBINS + bin];
    if (s) atomicAdd(&out[bin], (float)s);   // exact: integers < 2^24
}

__global__ void count_kernel(const void* __restrict__ bs_raw,
                             float* __restrict__ out) {
    const int as_int = *(const int*)bs_raw;
    float bs;
    if (as_int >= 1 && as_int < (1 << 20)) {
        bs = (float)as_int;
    } else {
        bs = *(const float*)bs_raw;
    }
    out[NBINS + threadIdx.x] = bs * out[0];
}

extern "C" void kernel_launch(void* const* d_in, const int* in_sizes, int n_in,
                              void* d_out, int out_size, void* d_ws, size_t ws_size,
                              hipStream_t stream) {
    const void* bs_ptr;
    const float* x;
    int n;
    if (n_in >= 2 && in_sizes[0] == 1) {
        bs_ptr = d_in[0];
        x = (const float*)d_in[1];
        n = in_sizes[1];
    } else {
        bs_ptr = d_in[1];
        x = (const float*)d_in[0];
        n = in_sizes[0];
    }

    float* out = (float*)d_out;                    // [256 hist | 256 count], float32
    unsigned int* partial = (unsigned int*)d_ws;   // [G][256] u32 partials

    const long n4 = (long)n >> 2;
    int G = (int)((n4 + (long)BLOCK * CAP_F4 - 1) / ((long)BLOCK * CAP_F4));
    if (G < 1) G = 1;

    const size_t ws_need = (size_t)G * NBINS * sizeof(unsigned int);
    const int use_ws = (ws_size >= ws_need) ? 1 : 0;

    zero_out<<<2, 256, 0, stream>>>(out);
    hist_kernel<<<G, BLOCK, 0, stream>>>(x, partial, out, n, G, use_ws);
    if (use_ws) {
        const int slice = (G + NBINS - 1) / NBINS;
        reduce_kernel<<<NBINS, NBINS, 0, stream>>>(partial, out, G, slice);
    }
    count_kernel<<<1, NBINS, 0, stream>>>(bs_ptr, out);
}